// Round 1
// baseline (225.024 us; speedup 1.0000x reference)
//
#include <hip/hip_runtime.h>

// Problem constants
#define NPAR   8192      // parents
#define NCH    65536     // children = NPAR*8
#define RES    32
#define EPS    1e-5f

typedef __attribute__((ext_vector_type(8))) short short8;
typedef __attribute__((ext_vector_type(4))) float floatx4;

__device__ __forceinline__ unsigned short f2bf(float f) {
    union { float f; unsigned u; } v; v.f = f;
    unsigned r = v.u + 0x7fffu + ((v.u >> 16) & 1u);   // RNE
    return (unsigned short)(r >> 16);
}
__device__ __forceinline__ float bf2f(unsigned short b) {
    union { unsigned u; float f; } v; v.u = ((unsigned)b) << 16;
    return v.f;
}
// async 16B global->LDS: per-lane global addr, wave-uniform LDS base (+lane*16)
__device__ __forceinline__ void glds16(const void* g, void* l) {
    __builtin_amdgcn_global_load_lds(
        (__attribute__((address_space(1))) const void*)g,
        (__attribute__((address_space(3))) void*)l, 16, 0, 0);
}
// parent-grid tap index for (child-offset o, slot s): e_a = o_a + s_a - 1
__device__ __forceinline__ int k27_of(int o, int s) {
    return (((o >> 2) & 1) + ((s >> 2) & 1)) * 9 +
           (((o >> 1) & 1) + ((s >> 1) & 1)) * 3 +
           ((o & 1) + (s & 1));
}
// fine-tap d-list per axis for (o,s) folding
__device__ __forceinline__ void axis_dlist(int o, int s, int* d, int& n) {
    if (o == 0) { if (s == 0) { d[0] = -1; n = 1; } else { d[0] = 0; d[1] = 1; n = 2; } }
    else        { if (s == 0) { d[0] = -1; d[1] = 0; n = 2; } else { d[0] = 1; n = 1; } }
}

// ---------------------------------------------------------------------------
// K1: blocks [0,32) scatter parents into grid32; blocks [32,288) GN1 stats.
__global__ void k1_kernel(const int* __restrict__ coords, int* __restrict__ grid32,
                          const float* __restrict__ x, float* __restrict__ sum,
                          float* __restrict__ sq) {
    int b = blockIdx.x;
    int t = threadIdx.x;
    if (b < 32) {
        int p = b * 256 + t;
        grid32[(coords[p*3] << 10) + (coords[p*3+1] << 5) + coords[p*3+2]] = p;
    } else {
        __shared__ float s_sum[32], s_sq[32];
        if (t < 32) { s_sum[t] = 0.0f; s_sq[t] = 0.0f; }
        __syncthreads();
        const float4* x4 = (const float4*)x;
        int total = NPAR * 32;
        int idx0 = (b - 32) * 256 + t;
        int g = idx0 & 31;
        float ls = 0.0f, lq = 0.0f;
        for (int idx = idx0; idx < total; idx += 256 * 256) {
            float4 v = x4[idx];
            ls += v.x + v.y + v.z + v.w;
            lq += v.x * v.x + v.y * v.y + v.z * v.z + v.w * v.w;
        }
        atomicAdd(&s_sum[g], ls);
        atomicAdd(&s_sq[g], lq);
        __syncthreads();
        if (t < 32) { atomicAdd(&sum[t], s_sum[t]); atomicAdd(&sq[t], s_sq[t]); }
    }
}

// ---------------------------------------------------------------------------
// K2, 2104 blocks: idx_tab / W2 pack / W1 fold+pack / pidx27 / GN1 apply
__global__ void k2_kernel(const int* __restrict__ coords, const int* __restrict__ grid32,
                          int* __restrict__ idx_tab, int* __restrict__ pidx27,
                          const float* __restrict__ W1, const float* __restrict__ W2,
                          unsigned short* __restrict__ Wc1f, unsigned short* __restrict__ Wp2,
                          const float* __restrict__ x, const float* __restrict__ sum,
                          const float* __restrict__ sq, const float* __restrict__ gamma,
                          const float* __restrict__ beta, unsigned short* __restrict__ y) {
    int b = blockIdx.x;
    if (b < 256) {
        int R = b * 256 + threadIdx.x;   // 65536
        int p = R >> 3, o = R & 7;
        int bx = 2 * coords[p*3]   + ((o >> 2) & 1);
        int by = 2 * coords[p*3+1] + ((o >> 1) & 1);
        int bz = 2 * coords[p*3+2] + (o & 1);
#pragma unroll 1
        for (int k = 0; k < 27; ++k) {
            int fx = bx + k / 9 - 1, fy = by + (k / 3) % 3 - 1, fz = bz + k % 3 - 1;
            int src = -1;
            if ((unsigned)fx < 64u && (unsigned)fy < 64u && (unsigned)fz < 64u) {
                int r = grid32[((fx >> 1) << 10) + ((fy >> 1) << 5) + (fz >> 1)];
                if ((unsigned)r < (unsigned)NPAR)
                    src = (((fx & 1) << 2) + ((fy & 1) << 1) + (fz & 1)) * NPAR + r;
            }
            idx_tab[k * NCH + R] = src;
        }
    } else if (b < 472) {
        int rem = (b - 256) * 256 + threadIdx.x;   // < 55296
        int lane = rem & 63;
        int ks   = (rem >> 6) & 3;
        int nb   = (rem >> 8) & 7;
        int tap  = rem >> 11;                       // 0..26
        int n  = nb * 16 + (lane & 15);
        int k0 = ks * 32 + (lane >> 4) * 8;
        unsigned short v[8];
#pragma unroll
        for (int j = 0; j < 8; ++j) v[j] = f2bf(W2[tap * 16384 + (k0 + j) * 128 + n]);
        uint4 pk;
        pk.x = (unsigned)v[0] | ((unsigned)v[1] << 16);
        pk.y = (unsigned)v[2] | ((unsigned)v[3] << 16);
        pk.z = (unsigned)v[4] | ((unsigned)v[5] << 16);
        pk.w = (unsigned)v[6] | ((unsigned)v[7] << 16);
        *(uint4*)&Wp2[(long)rem * 8] = pk;
    } else if (b < 984) {
        int rem = (b - 472) * 256 + threadIdx.x;   // < 131072
        int lane  = rem & 63;
        int ks    = (rem >> 6) & 3;
        int nb    = (rem >> 8) & 7;
        int combo = rem >> 11;                      // 0..63 = o*8+s
        int o = combo >> 3, s = combo & 7;
        int n  = nb * 16 + (lane & 15);
        int k0 = ks * 32 + (lane >> 4) * 8;
        int d0[2], d1[2], d2[2], n0, n1, n2;
        axis_dlist((o >> 2) & 1, (s >> 2) & 1, d0, n0);
        axis_dlist((o >> 1) & 1, (s >> 1) & 1, d1, n1);
        axis_dlist(o & 1,        s & 1,        d2, n2);
        unsigned short v[8];
#pragma unroll
        for (int j = 0; j < 8; ++j) {
            float acc = 0.0f;
            for (int a = 0; a < n0; ++a)
                for (int bb = 0; bb < n1; ++bb)
                    for (int cc = 0; cc < n2; ++cc) {
                        int kk = (d0[a] + 1) * 9 + (d1[bb] + 1) * 3 + (d2[cc] + 1);
                        acc += W1[kk * 16384 + (k0 + j) * 128 + n];
                    }
            v[j] = f2bf(acc);
        }
        uint4 pk;
        pk.x = (unsigned)v[0] | ((unsigned)v[1] << 16);
        pk.y = (unsigned)v[2] | ((unsigned)v[3] << 16);
        pk.z = (unsigned)v[4] | ((unsigned)v[5] << 16);
        pk.w = (unsigned)v[6] | ((unsigned)v[7] << 16);
        *(uint4*)&Wc1f[(long)rem * 8] = pk;
    } else if (b < 1848) {
        int gid = (b - 984) * 256 + threadIdx.x;   // < 221184 = 27*8192
        int k = gid >> 13, p = gid & 8191;
        int nx = coords[p*3]   + k / 9 - 1;
        int ny = coords[p*3+1] + (k / 3) % 3 - 1;
        int nz = coords[p*3+2] + k % 3 - 1;
        int src = -1;
        if ((unsigned)nx < 32u && (unsigned)ny < 32u && (unsigned)nz < 32u) {
            int r = grid32[(nx << 10) + (ny << 5) + nz];
            if ((unsigned)r < (unsigned)NPAR) src = r;
        }
        pidx27[k * NPAR + p] = src;
    } else {
        const float4* x4 = (const float4*)x;
        uint2* y2 = (uint2*)y;
        const float4* g4 = (const float4*)gamma;
        const float4* b4 = (const float4*)beta;
        float cnt = (float)NPAR * 4.0f;
        int total = NPAR * 32;
        for (int idx = (b - 1848) * 256 + threadIdx.x; idx < total; idx += 256 * 256) {
            int c4 = idx & 31;
            float mean = sum[c4] / cnt;
            float var = sq[c4] / cnt - mean * mean;
            float rstd = rsqrtf(var + EPS);
            float4 v = x4[idx];
            float4 gm = g4[c4];
            float4 bt = b4[c4];
            float a[4] = {v.x, v.y, v.z, v.w};
            float gg[4] = {gm.x, gm.y, gm.z, gm.w};
            float bb[4] = {bt.x, bt.y, bt.z, bt.w};
            unsigned short o[4];
#pragma unroll
            for (int i = 0; i < 4; ++i) {
                float tv = (a[i] - mean) * rstd * gg[i] + bb[i];
                o[i] = f2bf(tv / (1.0f + __expf(-tv)));
            }
            uint2 pk;
            pk.x = (unsigned)o[0] | ((unsigned)o[1] << 16);
            pk.y = (unsigned)o[2] | ((unsigned)o[3] << 16);
            y2[idx] = pk;
        }
    }
}

// ---------------------------------------------------------------------------
// bf16 in -> bf16 out, in place (GN2); layout-agnostic elementwise
__global__ void gn_apply_bf16_kernel(unsigned short* __restrict__ x,
                                     const float* __restrict__ sum, const float* __restrict__ sq,
                                     const float* __restrict__ gamma, const float* __restrict__ beta,
                                     int nrows) {
    uint2* x2 = (uint2*)x;
    const float4* g4 = (const float4*)gamma;
    const float4* b4 = (const float4*)beta;
    float cnt = (float)nrows * 4.0f;
    int total = nrows * 32;
    for (int idx = blockIdx.x * blockDim.x + threadIdx.x; idx < total;
         idx += gridDim.x * blockDim.x) {
        int c4 = idx & 31;
        float mean = sum[c4] / cnt;
        float var = sq[c4] / cnt - mean * mean;
        float rstd = rsqrtf(var + EPS);
        uint2 pk = x2[idx];
        float a[4] = {bf2f((unsigned short)(pk.x & 0xffff)), bf2f((unsigned short)(pk.x >> 16)),
                      bf2f((unsigned short)(pk.y & 0xffff)), bf2f((unsigned short)(pk.y >> 16))};
        float4 gm = g4[c4];
        float4 bt = b4[c4];
        float gg[4] = {gm.x, gm.y, gm.z, gm.w};
        float bb[4] = {bt.x, bt.y, bt.z, bt.w};
        unsigned short o[4];
#pragma unroll
        for (int i = 0; i < 4; ++i) {
            float tv = (a[i] - mean) * rstd * gg[i] + bb[i];
            o[i] = f2bf(tv / (1.0f + __expf(-tv)));
        }
        pk.x = (unsigned)o[0] | ((unsigned)o[1] << 16);
        pk.y = (unsigned)o[2] | ((unsigned)o[3] << 16);
        x2[idx] = pk;
    }
}

// ---------------------------------------------------------------------------
// Shared MFMA machinery — 256-row / 512-thread / 8-wave, 4-sub-phase schedule.
//
// LDS A layout (per buffer, 32768 shorts): [grp(16)][ks(4)][r16(16)][cch(4)][8]
// where grp = row>>4, r16 = row&15, and the 16B chunk stored at (r16,cch) holds
// source channels ks*32 + (cch ^ (r16>>2))*8  (XOR swizzle, applied on the
// GLOBAL source side since global_load_lds writes linearly: lane = r16*4+cch,
// lane>>4 == r16>>2).  The swizzled ds_read_b128 (quad ^= l16>>2) then makes
// each 16-lane group cover all 16 16B slots of the 256B bank row -> 2-way
// (free) instead of the previous 8-way conflict.

// B frags for one tap from packed W ([tap][nb][ks][lane][8] shorts)
__device__ __forceinline__ void loadB(const unsigned short* __restrict__ Wtap,
                                      short8 (&bfr)[4][4], int wn, int lane) {
#pragma unroll
    for (int nt = 0; nt < 4; ++nt)
#pragma unroll
        for (int ks = 0; ks < 4; ++ks)
            bfr[nt][ks] = *(const short8*)&Wtap[(((wn * 4 + nt) << 2) + ks) * 512 + (lane << 3)];
}

// 8x glds16: stage this wave's two 16-row groups of the next A tile.
// cchOff = (cch ^ quad) << 3  (pre-swizzled source chunk).
__device__ __forceinline__ void stage_cluster(const unsigned short* __restrict__ Ag,
                                              int iv0, int iv1, const unsigned short* zsrc,
                                              unsigned short* __restrict__ buf,
                                              int lb0, int lb1, int cchOff) {
    const unsigned short* g0 = (iv0 >= 0) ? Ag + (long)iv0 * 128 : zsrc;
    const unsigned short* g1 = (iv1 >= 0) ? Ag + (long)iv1 * 128 : zsrc;
#pragma unroll
    for (int i = 0; i < 4; ++i) {
        glds16(g0 + (i << 5) + cchOff, &buf[lb0 + (i << 9)]);
        glds16(g1 + (i << 5) + cchOff, &buf[lb1 + (i << 9)]);
    }
}

// One tap: glds cluster (next tap A) -> 4 phases of
// {ds_read A-frags(ks=p) || load B-next(.,p) ; s_barrier ; setprio+16 MFMA ;
//  s_barrier} ; trailing counted vmcnt(16)+s_barrier (16 = vmem ops issued
// after the glds cluster: 2 idx + 16 B in the worst case, so the wait retires
// exactly the 8 glds -- never a full drain; the fused asm's memory clobber
// pins every load on its side of the wait).
__device__ __forceinline__ void conv_tap(
    const unsigned short* __restrict__ Abuf, unsigned short* __restrict__ Nbuf,
    const unsigned short* __restrict__ Ag, const unsigned short* __restrict__ zsrc,
    const unsigned short* __restrict__ WbNext,
    const int* __restrict__ ivp0, const int* __restrict__ ivp1,
    int iv0, int iv1, int& pv0, int& pv1,
    short8 (&bCur)[4][4], short8 (&bNext)[4][4], floatx4 (&acc)[4][4],
    int wm, int wn, int lane, int l16, int quad,
    int lb0, int lb1, int cchOff, bool stage, bool pre2) {
    if (stage) stage_cluster(Ag, iv0, iv1, zsrc, Nbuf, lb0, lb1, cchOff);
    asm volatile("" ::: "memory");   // pin glds cluster position in vmcnt order
    if (pre2) { pv0 = *ivp0; pv1 = *ivp1; }
    int aswz = (l16 << 5) + ((quad ^ (l16 >> 2)) << 3);
#pragma unroll
    for (int p = 0; p < 4; ++p) {
        short8 afr[4];
#pragma unroll
        for (int mt = 0; mt < 4; ++mt)
            afr[mt] = *(const short8*)&Abuf[(((wm << 2) + mt) << 11) + (p << 9) + aswz];
        if (stage) {
#pragma unroll
            for (int nt = 0; nt < 4; ++nt)
                bNext[nt][p] = *(const short8*)&WbNext[((((wn << 2) + nt) << 2) + p) * 512 + (lane << 3)];
        }
        asm volatile("s_barrier" ::: "memory");
        __builtin_amdgcn_s_setprio(1);
#pragma unroll
        for (int mt = 0; mt < 4; ++mt)
#pragma unroll
            for (int nt = 0; nt < 4; ++nt)
                acc[mt][nt] = __builtin_amdgcn_mfma_f32_16x16x32_bf16(
                    afr[mt], bCur[nt][p], acc[mt][nt], 0, 0, 0);
        __builtin_amdgcn_s_setprio(0);
        if (p < 3) asm volatile("s_barrier" ::: "memory");
    }
    asm volatile("s_waitcnt vmcnt(16)\n\ts_barrier" ::: "memory");
}

// ---------------------------------------------------------------------------
// CONV1 FOLDED — 256 parents/block, 8 waves, 8 slots, 4-phase schedule.
__global__ void __launch_bounds__(512, 2) conv1_fold_kernel(
    const unsigned short* __restrict__ Ag, const unsigned short* __restrict__ Wc1f,
    const float* __restrict__ bias, const int* __restrict__ pidx27,
    unsigned short* __restrict__ outp, const float* __restrict__ zpage,
    float* __restrict__ gsum, float* __restrict__ gsq) {
    __shared__ unsigned short A_lds[2][32768];   // 2 x 64 KB

    int t = threadIdx.x;
    int o  = blockIdx.x & 7;
    int P0 = (blockIdx.x >> 3) << 8;            // 256 parents per block
    const unsigned short* Wb = Wc1f + ((long)o << 17);
    int wv = t >> 6, lane = t & 63, quad = lane >> 4, l16 = lane & 15;
    int wm = wv >> 1, wn = wv & 1;
    int r16 = lane >> 2, cch = lane & 3;
    int c0 = wv * 2, c1 = c0 + 1;
    int row0 = (c0 << 4) + r16, row1 = (c1 << 4) + r16;
    int lb0 = c0 << 11, lb1 = c1 << 11;
    int cchOff = (cch ^ quad) << 3;
    const unsigned short* zsrc = (const unsigned short*)zpage;

    floatx4 acc[4][4];
#pragma unroll
    for (int mt = 0; mt < 4; ++mt)
#pragma unroll
        for (int nt = 0; nt < 4; ++nt)
            acc[mt][nt] = (floatx4){0.f, 0.f, 0.f, 0.f};
    short8 bA[4][4], bB[4][4];

    // ---- prolog: slot 0 A -> buf0; idx(1); B(0) -> bA; counted wait + barrier
    {
        int iv0 = pidx27[k27_of(o, 0) * NPAR + P0 + row0];
        int iv1 = pidx27[k27_of(o, 0) * NPAR + P0 + row1];
        stage_cluster(Ag, iv0, iv1, zsrc, A_lds[0], lb0, lb1, cchOff);
    }
    asm volatile("" ::: "memory");
    int nv0 = pidx27[k27_of(o, 1) * NPAR + P0 + row0];
    int nv1 = pidx27[k27_of(o, 1) * NPAR + P0 + row1];
    loadB(Wb, bA, wn, lane);
    asm volatile("s_waitcnt vmcnt(16)\n\ts_barrier" ::: "memory");

    int pv0 = -1, pv1 = -1;
#pragma unroll 1
    for (int s = 0; s < 8; s += 2) {
        conv_tap(A_lds[0], A_lds[1], Ag, zsrc, Wb + ((long)(s + 1) << 14),
                 pidx27 + (long)k27_of(o, (s + 2) & 7) * NPAR + P0 + row0,
                 pidx27 + (long)k27_of(o, (s + 2) & 7) * NPAR + P0 + row1,
                 nv0, nv1, pv0, pv1, bA, bB, acc,
                 wm, wn, lane, l16, quad, lb0, lb1, cchOff, true, s + 2 < 8);
        nv0 = pv0; nv1 = pv1;
        conv_tap(A_lds[1], A_lds[0], Ag, zsrc, Wb + ((long)(s + 2) << 14),
                 pidx27 + (long)k27_of(o, (s + 3) & 7) * NPAR + P0 + row0,
                 pidx27 + (long)k27_of(o, (s + 3) & 7) * NPAR + P0 + row1,
                 nv0, nv1, pv0, pv1, bB, bA, acc,
                 wm, wn, lane, l16, quad, lb0, lb1, cchOff, s + 2 < 8, s + 3 < 8);
        nv0 = pv0; nv1 = pv1;
    }

    // ---- epilogue: coalesced bf16 store at row o*NPAR + p, fused GN2 stats
    float s_[4] = {0.f, 0.f, 0.f, 0.f}, q_[4] = {0.f, 0.f, 0.f, 0.f};
#pragma unroll
    for (int nt = 0; nt < 4; ++nt) {
        int col = wn * 64 + nt * 16 + l16;
        float bv = bias[col];
#pragma unroll
        for (int mt = 0; mt < 4; ++mt) {
#pragma unroll
            for (int r = 0; r < 4; ++r) {
                int prow = wm * 64 + mt * 16 + quad * 4 + r;
                long R = (long)o * NPAR + P0 + prow;
                float v = acc[mt][nt][r] + bv;
                unsigned short u = f2bf(v);
                outp[R * 128 + col] = u;
                float vr = bf2f(u);
                s_[nt] += vr;
                q_[nt] += vr * vr;
            }
        }
    }
    float* sred = (float*)A_lds;   // safe: tap's trailing barrier passed
    if (t < 64) sred[t] = 0.0f;
    __syncthreads();
#pragma unroll
    for (int nt = 0; nt < 4; ++nt) {
        int g = (wn * 64 + nt * 16 + l16) >> 2;
        atomicAdd(&sred[g], s_[nt]);
        atomicAdd(&sred[32 + g], q_[nt]);
    }
    __syncthreads();
    if (t < 32) { atomicAdd(&gsum[t], sred[t]); atomicAdd(&gsq[t], sred[32 + t]); }
}

// ---------------------------------------------------------------------------
// CONV2 — 256 children/block, 8 waves, 27 taps, 4-phase schedule.
__global__ void __launch_bounds__(512, 2) conv2_kernel(
    const unsigned short* __restrict__ Ag, const unsigned short* __restrict__ Wp,
    const float* __restrict__ bias, const int* __restrict__ idx_tab,
    const float* __restrict__ resid, float* __restrict__ outp,
    const float* __restrict__ zpage) {
    __shared__ unsigned short A_lds[2][32768];   // 2 x 64 KB

    int t = threadIdx.x;
    int R0 = blockIdx.x << 8;                   // 256 rows per block
    int wv = t >> 6, lane = t & 63, quad = lane >> 4, l16 = lane & 15;
    int wm = wv >> 1, wn = wv & 1;
    int r16 = lane >> 2, cch = lane & 3;
    int c0 = wv * 2, c1 = c0 + 1;
    int row0 = (c0 << 4) + r16, row1 = (c1 << 4) + r16;
    int lb0 = c0 << 11, lb1 = c1 << 11;
    int cchOff = (cch ^ quad) << 3;
    const unsigned short* zsrc = (const unsigned short*)zpage;

    floatx4 acc[4][4];
#pragma unroll
    for (int mt = 0; mt < 4; ++mt)
#pragma unroll
        for (int nt = 0; nt < 4; ++nt)
            acc[mt][nt] = (floatx4){0.f, 0.f, 0.f, 0.f};
    short8 bA[4][4], bB[4][4];

    // ---- prolog: tap 0 A -> buf0; idx(1); B(0) -> bA; counted wait + barrier
    {
        int iv0 = idx_tab[R0 + row0], iv1 = idx_tab[R0 + row1];
        stage_cluster(Ag, iv0, iv1, zsrc, A_lds[0], lb0, lb1, cchOff);
    }
    asm volatile("" ::: "memory");
    int nv0 = idx_tab[NCH + R0 + row0], nv1 = idx_tab[NCH + R0 + row1];
    loadB(Wp, bA, wn, lane);
    asm volatile("s_waitcnt vmcnt(16)\n\ts_barrier" ::: "memory");

    int pv0 = -1, pv1 = -1;
#pragma unroll 1
    for (int k = 0; k < 26; k += 2) {
        conv_tap(A_lds[0], A_lds[1], Ag, zsrc, Wp + ((long)(k + 1) << 14),
                 idx_tab + (long)(k + 2) * NCH + R0 + row0,
                 idx_tab + (long)(k + 2) * NCH + R0 + row1,
                 nv0, nv1, pv0, pv1, bA, bB, acc,
                 wm, wn, lane, l16, quad, lb0, lb1, cchOff, true, true);
        nv0 = pv0; nv1 = pv1;
        int k3 = (k + 3 < 27) ? k + 3 : 26;
        conv_tap(A_lds[1], A_lds[0], Ag, zsrc, Wp + ((long)(k + 2) << 14),
                 idx_tab + (long)k3 * NCH + R0 + row0,
                 idx_tab + (long)k3 * NCH + R0 + row1,
                 nv0, nv1, pv0, pv1, bB, bA, acc,
                 wm, wn, lane, l16, quad, lb0, lb1, cchOff, true, k + 3 < 27);
        nv0 = pv0; nv1 = pv1;
    }
    // tail tap 26 (reads buf0, bA, no staging)
    conv_tap(A_lds[0], A_lds[1], Ag, zsrc, Wp,
             idx_tab, idx_tab, -1, -1, pv0, pv1, bA, bB, acc,
             wm, wn, lane, l16, quad, lb0, lb1, cchOff, false, false);

#pragma unroll
    for (int nt = 0; nt < 4; ++nt) {
        int col = wn * 64 + nt * 16 + l16;
        float bv = bias[col];
#pragma unroll
        for (int mt = 0; mt < 4; ++mt) {
#pragma unroll
            for (int r = 0; r < 4; ++r) {
                int row = wm * 64 + mt * 16 + quad * 4 + r;
                long R = (long)R0 + row;
                float v = acc[mt][nt][r] + bv + resid[(R >> 3) * 128 + col];
                outp[R * 128 + col] = v;
            }
        }
    }
}

// ---------------------------------------------------------------------------
extern "C" void kernel_launch(void* const* d_in, const int* in_sizes, int n_in,
                              void* d_out, int out_size, void* d_ws, size_t ws_size,
                              hipStream_t stream) {
    const float* feats  = (const float*)d_in[0];
    const float* gamma1 = (const float*)d_in[1];
    const float* beta1  = (const float*)d_in[2];
    const float* W1     = (const float*)d_in[3];
    const float* b1     = (const float*)d_in[4];
    const float* gamma2 = (const float*)d_in[5];
    const float* beta2  = (const float*)d_in[6];
    const float* W2     = (const float*)d_in[7];
    const float* b2     = (const float*)d_in[8];
    const int*   coords = (const int*)d_in[9];
    float* out = (float*)d_out;   // 65536 x 128 fp32 (written only by conv2)

    char* ws = (char*)d_ws;
    unsigned short* h0b  = (unsigned short*)(ws);                    // 2 MB
    unsigned short* h1b  = (unsigned short*)(ws + (2u << 20));       // 16 MB, (o,p) layout
    unsigned short* Wc1f = (unsigned short*)(ws + (18u << 20));      // 2 MB
    unsigned short* Wp2  = (unsigned short*)(ws + (20u << 20));      // 864 KB
    int*   grid32        = (int*)  (ws + (21u << 20));               // 128 KB
    float* stats         = (float*)(ws + (21u << 20) + 131072);      // 512 B
    float* zpage         = (float*)(ws + (21u << 20) + 131072 + 512);// 512 B
    int*   idx_tab       = (int*)  (ws + (22u << 20));               // 7.08 MB
    int*   pidx27        = (int*)  (ws + (30u << 20));               // 864 KB

    // zero stats (128 f) + zpage (128 f) in one async memset
    hipMemsetAsync(stats, 0, 1024, stream);

    k1_kernel<<<288, 256, 0, stream>>>(coords, grid32, feats, stats + 0, stats + 32);
    k2_kernel<<<2104, 256, 0, stream>>>(coords, grid32, idx_tab, pidx27,
                                        W1, W2, Wc1f, Wp2,
                                        feats, stats + 0, stats + 32, gamma1, beta1, h0b);

    // conv1 folded -> bf16 h1b in (o,p) layout + fused GN2 stats
    conv1_fold_kernel<<<8 * (NPAR / 256), 512, 0, stream>>>(h0b, Wc1f, b1, pidx27,
                                                            h1b, zpage,
                                                            stats + 64, stats + 96);

    gn_apply_bf16_kernel<<<1024, 256, 0, stream>>>(h1b, stats + 64, stats + 96, gamma2, beta2, NCH);

    // conv2 (27 taps over children) -> fp32 out + residual repeat(feats,8)
    conv2_kernel<<<NCH / 256, 512, 0, stream>>>(h1b, Wp2, b2, idx_tab,
                                                feats, out, zpage);
}

// Round 2
// 206.868 us; speedup vs baseline: 1.0878x; 1.0878x over previous
//
#include <hip/hip_runtime.h>

// Problem constants
#define NPAR   8192      // parents
#define NCH    65536     // children = NPAR*8
#define RES    32
#define EPS    1e-5f

typedef __attribute__((ext_vector_type(8))) short short8;
typedef __attribute__((ext_vector_type(4))) float floatx4;

__device__ __forceinline__ unsigned short f2bf(float f) {
    union { float f; unsigned u; } v; v.f = f;
    unsigned r = v.u + 0x7fffu + ((v.u >> 16) & 1u);   // RNE
    return (unsigned short)(r >> 16);
}
__device__ __forceinline__ float bf2f(unsigned short b) {
    union { unsigned u; float f; } v; v.u = ((unsigned)b) << 16;
    return v.f;
}
// async 16B global->LDS: per-lane global addr, wave-uniform LDS base (+lane*16)
__device__ __forceinline__ void glds16(const void* g, void* l) {
    __builtin_amdgcn_global_load_lds(
        (__attribute__((address_space(1))) const void*)g,
        (__attribute__((address_space(3))) void*)l, 16, 0, 0);
}
// parent-grid tap index for (child-offset o, slot s): e_a = o_a + s_a - 1
__device__ __forceinline__ int k27_of(int o, int s) {
    return (((o >> 2) & 1) + ((s >> 2) & 1)) * 9 +
           (((o >> 1) & 1) + ((s >> 1) & 1)) * 3 +
           ((o & 1) + (s & 1));
}
// fine-tap d-list per axis for (o,s) folding
__device__ __forceinline__ void axis_dlist(int o, int s, int* d, int& n) {
    if (o == 0) { if (s == 0) { d[0] = -1; n = 1; } else { d[0] = 0; d[1] = 1; n = 2; } }
    else        { if (s == 0) { d[0] = -1; d[1] = 0; n = 2; } else { d[0] = 1; n = 1; } }
}

// ---------------------------------------------------------------------------
// K1: blocks [0,32) scatter parents into grid32; blocks [32,288) GN1 stats.
__global__ void k1_kernel(const int* __restrict__ coords, int* __restrict__ grid32,
                          const float* __restrict__ x, float* __restrict__ sum,
                          float* __restrict__ sq) {
    int b = blockIdx.x;
    int t = threadIdx.x;
    if (b < 32) {
        int p = b * 256 + t;
        grid32[(coords[p*3] << 10) + (coords[p*3+1] << 5) + coords[p*3+2]] = p;
    } else {
        __shared__ float s_sum[32], s_sq[32];
        if (t < 32) { s_sum[t] = 0.0f; s_sq[t] = 0.0f; }
        __syncthreads();
        const float4* x4 = (const float4*)x;
        int total = NPAR * 32;
        int idx0 = (b - 32) * 256 + t;
        int g = idx0 & 31;
        float ls = 0.0f, lq = 0.0f;
        for (int idx = idx0; idx < total; idx += 256 * 256) {
            float4 v = x4[idx];
            ls += v.x + v.y + v.z + v.w;
            lq += v.x * v.x + v.y * v.y + v.z * v.z + v.w * v.w;
        }
        atomicAdd(&s_sum[g], ls);
        atomicAdd(&s_sq[g], lq);
        __syncthreads();
        if (t < 32) { atomicAdd(&sum[t], s_sum[t]); atomicAdd(&sq[t], s_sq[t]); }
    }
}

// ---------------------------------------------------------------------------
// K2, 2104 blocks: idx_tab / W2 pack / W1 fold+pack / pidx27 / GN1 apply
__global__ void k2_kernel(const int* __restrict__ coords, const int* __restrict__ grid32,
                          int* __restrict__ idx_tab, int* __restrict__ pidx27,
                          const float* __restrict__ W1, const float* __restrict__ W2,
                          unsigned short* __restrict__ Wc1f, unsigned short* __restrict__ Wp2,
                          const float* __restrict__ x, const float* __restrict__ sum,
                          const float* __restrict__ sq, const float* __restrict__ gamma,
                          const float* __restrict__ beta, unsigned short* __restrict__ y) {
    int b = blockIdx.x;
    if (b < 256) {
        int R = b * 256 + threadIdx.x;   // 65536
        int p = R >> 3, o = R & 7;
        int bx = 2 * coords[p*3]   + ((o >> 2) & 1);
        int by = 2 * coords[p*3+1] + ((o >> 1) & 1);
        int bz = 2 * coords[p*3+2] + (o & 1);
#pragma unroll 1
        for (int k = 0; k < 27; ++k) {
            int fx = bx + k / 9 - 1, fy = by + (k / 3) % 3 - 1, fz = bz + k % 3 - 1;
            int src = -1;
            if ((unsigned)fx < 64u && (unsigned)fy < 64u && (unsigned)fz < 64u) {
                int r = grid32[((fx >> 1) << 10) + ((fy >> 1) << 5) + (fz >> 1)];
                if ((unsigned)r < (unsigned)NPAR)
                    src = (((fx & 1) << 2) + ((fy & 1) << 1) + (fz & 1)) * NPAR + r;
            }
            idx_tab[k * NCH + R] = src;
        }
    } else if (b < 472) {
        int rem = (b - 256) * 256 + threadIdx.x;   // < 55296
        int lane = rem & 63;
        int ks   = (rem >> 6) & 3;
        int nb   = (rem >> 8) & 7;
        int tap  = rem >> 11;                       // 0..26
        int n  = nb * 16 + (lane & 15);
        int k0 = ks * 32 + (lane >> 4) * 8;
        unsigned short v[8];
#pragma unroll
        for (int j = 0; j < 8; ++j) v[j] = f2bf(W2[tap * 16384 + (k0 + j) * 128 + n]);
        uint4 pk;
        pk.x = (unsigned)v[0] | ((unsigned)v[1] << 16);
        pk.y = (unsigned)v[2] | ((unsigned)v[3] << 16);
        pk.z = (unsigned)v[4] | ((unsigned)v[5] << 16);
        pk.w = (unsigned)v[6] | ((unsigned)v[7] << 16);
        *(uint4*)&Wp2[(long)rem * 8] = pk;
    } else if (b < 984) {
        int rem = (b - 472) * 256 + threadIdx.x;   // < 131072
        int lane  = rem & 63;
        int ks    = (rem >> 6) & 3;
        int nb    = (rem >> 8) & 7;
        int combo = rem >> 11;                      // 0..63 = o*8+s
        int o = combo >> 3, s = combo & 7;
        int n  = nb * 16 + (lane & 15);
        int k0 = ks * 32 + (lane >> 4) * 8;
        int d0[2], d1[2], d2[2], n0, n1, n2;
        axis_dlist((o >> 2) & 1, (s >> 2) & 1, d0, n0);
        axis_dlist((o >> 1) & 1, (s >> 1) & 1, d1, n1);
        axis_dlist(o & 1,        s & 1,        d2, n2);
        unsigned short v[8];
#pragma unroll
        for (int j = 0; j < 8; ++j) {
            float acc = 0.0f;
            for (int a = 0; a < n0; ++a)
                for (int bb = 0; bb < n1; ++bb)
                    for (int cc = 0; cc < n2; ++cc) {
                        int kk = (d0[a] + 1) * 9 + (d1[bb] + 1) * 3 + (d2[cc] + 1);
                        acc += W1[kk * 16384 + (k0 + j) * 128 + n];
                    }
            v[j] = f2bf(acc);
        }
        uint4 pk;
        pk.x = (unsigned)v[0] | ((unsigned)v[1] << 16);
        pk.y = (unsigned)v[2] | ((unsigned)v[3] << 16);
        pk.z = (unsigned)v[4] | ((unsigned)v[5] << 16);
        pk.w = (unsigned)v[6] | ((unsigned)v[7] << 16);
        *(uint4*)&Wc1f[(long)rem * 8] = pk;
    } else if (b < 1848) {
        int gid = (b - 984) * 256 + threadIdx.x;   // < 221184 = 27*8192
        int k = gid >> 13, p = gid & 8191;
        int nx = coords[p*3]   + k / 9 - 1;
        int ny = coords[p*3+1] + (k / 3) % 3 - 1;
        int nz = coords[p*3+2] + k % 3 - 1;
        int src = -1;
        if ((unsigned)nx < 32u && (unsigned)ny < 32u && (unsigned)nz < 32u) {
            int r = grid32[(nx << 10) + (ny << 5) + nz];
            if ((unsigned)r < (unsigned)NPAR) src = r;
        }
        pidx27[k * NPAR + p] = src;
    } else {
        const float4* x4 = (const float4*)x;
        uint2* y2 = (uint2*)y;
        const float4* g4 = (const float4*)gamma;
        const float4* b4 = (const float4*)beta;
        float cnt = (float)NPAR * 4.0f;
        int total = NPAR * 32;
        for (int idx = (b - 1848) * 256 + threadIdx.x; idx < total; idx += 256 * 256) {
            int c4 = idx & 31;
            float mean = sum[c4] / cnt;
            float var = sq[c4] / cnt - mean * mean;
            float rstd = rsqrtf(var + EPS);
            float4 v = x4[idx];
            float4 gm = g4[c4];
            float4 bt = b4[c4];
            float a[4] = {v.x, v.y, v.z, v.w};
            float gg[4] = {gm.x, gm.y, gm.z, gm.w};
            float bb[4] = {bt.x, bt.y, bt.z, bt.w};
            unsigned short o[4];
#pragma unroll
            for (int i = 0; i < 4; ++i) {
                float tv = (a[i] - mean) * rstd * gg[i] + bb[i];
                o[i] = f2bf(tv / (1.0f + __expf(-tv)));
            }
            uint2 pk;
            pk.x = (unsigned)o[0] | ((unsigned)o[1] << 16);
            pk.y = (unsigned)o[2] | ((unsigned)o[3] << 16);
            y2[idx] = pk;
        }
    }
}

// ---------------------------------------------------------------------------
// bf16 in -> bf16 out, in place (GN2); layout-agnostic elementwise
__global__ void gn_apply_bf16_kernel(unsigned short* __restrict__ x,
                                     const float* __restrict__ sum, const float* __restrict__ sq,
                                     const float* __restrict__ gamma, const float* __restrict__ beta,
                                     int nrows) {
    uint2* x2 = (uint2*)x;
    const float4* g4 = (const float4*)gamma;
    const float4* b4 = (const float4*)beta;
    float cnt = (float)nrows * 4.0f;
    int total = nrows * 32;
    for (int idx = blockIdx.x * blockDim.x + threadIdx.x; idx < total;
         idx += gridDim.x * blockDim.x) {
        int c4 = idx & 31;
        float mean = sum[c4] / cnt;
        float var = sq[c4] / cnt - mean * mean;
        float rstd = rsqrtf(var + EPS);
        uint2 pk = x2[idx];
        float a[4] = {bf2f((unsigned short)(pk.x & 0xffff)), bf2f((unsigned short)(pk.x >> 16)),
                      bf2f((unsigned short)(pk.y & 0xffff)), bf2f((unsigned short)(pk.y >> 16))};
        float4 gm = g4[c4];
        float4 bt = b4[c4];
        float gg[4] = {gm.x, gm.y, gm.z, gm.w};
        float bb[4] = {bt.x, bt.y, bt.z, bt.w};
        unsigned short o[4];
#pragma unroll
        for (int i = 0; i < 4; ++i) {
            float tv = (a[i] - mean) * rstd * gg[i] + bb[i];
            o[i] = f2bf(tv / (1.0f + __expf(-tv)));
        }
        pk.x = (unsigned)o[0] | ((unsigned)o[1] << 16);
        pk.y = (unsigned)o[2] | ((unsigned)o[3] << 16);
        x2[idx] = pk;
    }
}

// ---------------------------------------------------------------------------
// Shared MFMA helpers.
//
// LDS A layout (per buffer): [grp(8)][ks(4)][r16(16)][cch(4)][8 shorts].
// Bank-conflict fix (quarter-wave analysis): the 16B chunk stored at
// (r16, cch) holds source channels ks*32 + (cch ^ ((r16>>1)&3))*8 — the XOR
// is applied on the GLOBAL source address (global_load_lds writes linearly,
// lane = r16*4+cch), and undone on the ds_read side
// (swz = quad ^ ((l16>>1)&3)).  Within a 16-lane quarter-wave (quad const,
// l16=0..15) the 16B-slot index becomes 4*(l16&1) + (quad ^ ((l16>>1)&3)):
// each of the 8 slots gets exactly 2 lanes -> 2-way (free) instead of 8-way.
__device__ __forceinline__ void mfma_phase(
    const unsigned short* __restrict__ Abuf, short8 (&bfr)[4][4],
    floatx4 (&acc)[4][4], int wm, int aswz) {
#pragma unroll
    for (int ks = 0; ks < 4; ++ks) {
        short8 afr[4];
#pragma unroll
        for (int mt = 0; mt < 4; ++mt)
            afr[mt] = *(const short8*)&Abuf[(wm << 13) + (mt << 11) + (ks << 9) + aswz];
#pragma unroll
        for (int mt = 0; mt < 4; ++mt)
#pragma unroll
            for (int nt = 0; nt < 4; ++nt)
                acc[mt][nt] = __builtin_amdgcn_mfma_f32_16x16x32_bf16(
                    afr[mt], bfr[nt][ks], acc[mt][nt], 0, 0, 0);
    }
}
__device__ __forceinline__ void loadB(const unsigned short* __restrict__ Wtap,
                                      short8 (&bfr)[4][4], int wn, int lane) {
#pragma unroll
    for (int nt = 0; nt < 4; ++nt)
#pragma unroll
        for (int ks = 0; ks < 4; ++ks)
            bfr[nt][ks] = *(const short8*)&Wtap[(((wn * 4 + nt) << 2) + ks) * 512 + (lane << 3)];
}
__device__ __forceinline__ void stageA(const unsigned short* __restrict__ Ag,
                                       int iv0, int iv1, const unsigned short* zsrc,
                                       unsigned short* __restrict__ buf,
                                       int base0, int base1, int cchOff) {
    const unsigned short* g0 = (iv0 >= 0) ? Ag + (long)iv0 * 128 : zsrc;
    const unsigned short* g1 = (iv1 >= 0) ? Ag + (long)iv1 * 128 : zsrc;
#pragma unroll
    for (int i = 0; i < 4; ++i) glds16(g0 + i * 32 + cchOff, &buf[base0 + i * 512]);
#pragma unroll
    for (int i = 0; i < 4; ++i) glds16(g1 + i * 32 + cchOff, &buf[base1 + i * 512]);
}

// ---------------------------------------------------------------------------
// CONV1 FOLDED — 2x-unrolled slot loop, ping-pong B register sets (bA/bB, no
// copies) so the compiler must keep the prefetched B set live across the
// barrier.
__global__ void __launch_bounds__(256, 2) conv1_fold_kernel(
    const unsigned short* __restrict__ Ag, const unsigned short* __restrict__ Wc1f,
    const float* __restrict__ bias, const int* __restrict__ pidx27,
    unsigned short* __restrict__ outp, const float* __restrict__ zpage,
    float* __restrict__ gsum, float* __restrict__ gsq) {
    __shared__ unsigned short A_lds[2][16384];   // 2 x 32 KB

    int t = threadIdx.x;
    int o  = blockIdx.x & 7;
    int P0 = (blockIdx.x >> 3) << 7;            // 128 parents per block
    const unsigned short* Wb = Wc1f + ((long)o << 17);
    int wv = t >> 6, lane = t & 63, quad = lane >> 4, l16 = lane & 15;
    int wm = wv & 1, wn = wv >> 1;
    int r16 = lane >> 2, cch = lane & 3;
    int c0 = wv * 2, c1 = wv * 2 + 1;
    int row0 = ((c0 >> 2) << 6) + ((c0 & 3) << 4) + r16;
    int row1 = ((c1 >> 2) << 6) + ((c1 & 3) << 4) + r16;
    int base0 = ((c0 >> 2) << 13) + ((c0 & 3) << 11);
    int base1 = ((c1 >> 2) << 13) + ((c1 & 3) << 11);
    int cchOff = (cch ^ ((r16 >> 1) & 3)) << 3;            // swizzled source chunk
    int aswz = (l16 << 5) + ((quad ^ ((l16 >> 1) & 3)) << 3);  // swizzled read
    const unsigned short* zsrc = (const unsigned short*)zpage;

    floatx4 acc[4][4];
#pragma unroll
    for (int mt = 0; mt < 4; ++mt)
#pragma unroll
        for (int nt = 0; nt < 4; ++nt)
            acc[mt][nt] = (floatx4){0.f, 0.f, 0.f, 0.f};
    short8 bA[4][4], bB[4][4];

    // ---- prolog: slot 0 A -> buf0, slot 0 B -> bA
    stageA(Ag, pidx27[k27_of(o, 0) * NPAR + P0 + row0],
               pidx27[k27_of(o, 0) * NPAR + P0 + row1], zsrc, A_lds[0], base0, base1, cchOff);
    loadB(Wb, bA, wn, lane);
    int nv0 = pidx27[k27_of(o, 1) * NPAR + P0 + row0];
    int nv1 = pidx27[k27_of(o, 1) * NPAR + P0 + row1];
    __syncthreads();

#pragma unroll 1
    for (int s = 0; s < 8; s += 2) {
        // phase A: slot s from buf0/bA; stage slot s+1 -> buf1, B(s+1) -> bB
        stageA(Ag, nv0, nv1, zsrc, A_lds[1], base0, base1, cchOff);
        loadB(Wb + ((long)(s + 1) << 14), bB, wn, lane);
        if (s + 2 < 8) {
            nv0 = pidx27[k27_of(o, s + 2) * NPAR + P0 + row0];
            nv1 = pidx27[k27_of(o, s + 2) * NPAR + P0 + row1];
        }
        mfma_phase(A_lds[0], bA, acc, wm, aswz);
        __syncthreads();
        // phase B: slot s+1 from buf1/bB; stage slot s+2 -> buf0, B(s+2) -> bA
        if (s + 2 < 8) {
            stageA(Ag, nv0, nv1, zsrc, A_lds[0], base0, base1, cchOff);
            loadB(Wb + ((long)(s + 2) << 14), bA, wn, lane);
            if (s + 3 < 8) {
                nv0 = pidx27[k27_of(o, s + 3) * NPAR + P0 + row0];
                nv1 = pidx27[k27_of(o, s + 3) * NPAR + P0 + row1];
            }
        }
        mfma_phase(A_lds[1], bB, acc, wm, aswz);
        __syncthreads();
    }

    // ---- epilogue: coalesced bf16 store at row o*NPAR + p, fused GN2 stats
    float s_[4] = {0.f, 0.f, 0.f, 0.f}, q_[4] = {0.f, 0.f, 0.f, 0.f};
#pragma unroll
    for (int nt = 0; nt < 4; ++nt) {
        int col = wn * 64 + nt * 16 + l16;
        float bv = bias[col];
#pragma unroll
        for (int mt = 0; mt < 4; ++mt) {
#pragma unroll
            for (int r = 0; r < 4; ++r) {
                int prow = wm * 64 + mt * 16 + quad * 4 + r;
                long R = (long)o * NPAR + P0 + prow;
                float v = acc[mt][nt][r] + bv;
                unsigned short u = f2bf(v);
                outp[R * 128 + col] = u;
                float vr = bf2f(u);
                s_[nt] += vr;
                q_[nt] += vr * vr;
            }
        }
    }
    float* sred = (float*)A_lds;   // safe: loop's trailing barrier passed
    if (t < 64) sred[t] = 0.0f;
    __syncthreads();
#pragma unroll
    for (int nt = 0; nt < 4; ++nt) {
        int g = (wn * 64 + nt * 16 + l16) >> 2;
        atomicAdd(&sred[g], s_[nt]);
        atomicAdd(&sred[32 + g], q_[nt]);
    }
    __syncthreads();
    if (t < 32) { atomicAdd(&gsum[t], sred[t]); atomicAdd(&gsq[t], sred[32 + t]); }
}

// ---------------------------------------------------------------------------
// CONV2 — 2x-unrolled tap loop with ping-pong B register sets (no copies).
__global__ void __launch_bounds__(256, 2) conv2_kernel(
    const unsigned short* __restrict__ Ag, const unsigned short* __restrict__ Wp,
    const float* __restrict__ bias, const int* __restrict__ idx_tab,
    const float* __restrict__ resid, float* __restrict__ outp,
    const float* __restrict__ zpage) {
    __shared__ unsigned short A_lds[2][16384];   // 2 x 32 KB

    int t = threadIdx.x;
    int R0 = blockIdx.x * 128;
    int wv = t >> 6, lane = t & 63, quad = lane >> 4, l16 = lane & 15;
    int wm = wv & 1, wn = wv >> 1;
    int r16 = lane >> 2, cch = lane & 3;
    int c0 = wv * 2, c1 = wv * 2 + 1;
    int row0 = ((c0 >> 2) << 6) + ((c0 & 3) << 4) + r16;
    int row1 = ((c1 >> 2) << 6) + ((c1 & 3) << 4) + r16;
    int base0 = ((c0 >> 2) << 13) + ((c0 & 3) << 11);
    int base1 = ((c1 >> 2) << 13) + ((c1 & 3) << 11);
    int cchOff = (cch ^ ((r16 >> 1) & 3)) << 3;            // swizzled source chunk
    int aswz = (l16 << 5) + ((quad ^ ((l16 >> 1) & 3)) << 3);  // swizzled read
    const unsigned short* zsrc = (const unsigned short*)zpage;

    floatx4 acc[4][4];
#pragma unroll
    for (int mt = 0; mt < 4; ++mt)
#pragma unroll
        for (int nt = 0; nt < 4; ++nt)
            acc[mt][nt] = (floatx4){0.f, 0.f, 0.f, 0.f};
    short8 bA[4][4], bB[4][4];

    // ---- prolog: tap 0 A -> buf0, tap 0 B -> bA
    stageA(Ag, idx_tab[R0 + row0], idx_tab[R0 + row1], zsrc, A_lds[0], base0, base1, cchOff);
    loadB(Wp, bA, wn, lane);
    int nv0 = idx_tab[NCH + R0 + row0], nv1 = idx_tab[NCH + R0 + row1];
    __syncthreads();

#pragma unroll 1
    for (int k = 0; k < 27; k += 2) {
        // phase A: tap k from buf0/bA
        if (k + 1 < 27) {
            stageA(Ag, nv0, nv1, zsrc, A_lds[1], base0, base1, cchOff);
            loadB(Wp + ((long)(k + 1) << 14), bB, wn, lane);
            if (k + 2 < 27) {
                nv0 = idx_tab[(k + 2) * NCH + R0 + row0];
                nv1 = idx_tab[(k + 2) * NCH + R0 + row1];
            }
        }
        mfma_phase(A_lds[0], bA, acc, wm, aswz);
        __syncthreads();
        // phase B: tap k+1 from buf1/bB
        if (k + 1 < 27) {
            if (k + 2 < 27) {
                stageA(Ag, nv0, nv1, zsrc, A_lds[0], base0, base1, cchOff);
                loadB(Wp + ((long)(k + 2) << 14), bA, wn, lane);
                if (k + 3 < 27) {
                    nv0 = idx_tab[(k + 3) * NCH + R0 + row0];
                    nv1 = idx_tab[(k + 3) * NCH + R0 + row1];
                }
            }
            mfma_phase(A_lds[1], bB, acc, wm, aswz);
            __syncthreads();
        }
    }

#pragma unroll
    for (int nt = 0; nt < 4; ++nt) {
        int col = wn * 64 + nt * 16 + l16;
        float bv = bias[col];
#pragma unroll
        for (int mt = 0; mt < 4; ++mt) {
#pragma unroll
            for (int r = 0; r < 4; ++r) {
                int row = wm * 64 + mt * 16 + quad * 4 + r;
                long R = (long)R0 + row;
                float v = acc[mt][nt][r] + bv + resid[(R >> 3) * 128 + col];
                outp[R * 128 + col] = v;
            }
        }
    }
}

// ---------------------------------------------------------------------------
extern "C" void kernel_launch(void* const* d_in, const int* in_sizes, int n_in,
                              void* d_out, int out_size, void* d_ws, size_t ws_size,
                              hipStream_t stream) {
    const float* feats  = (const float*)d_in[0];
    const float* gamma1 = (const float*)d_in[1];
    const float* beta1  = (const float*)d_in[2];
    const float* W1     = (const float*)d_in[3];
    const float* b1     = (const float*)d_in[4];
    const float* gamma2 = (const float*)d_in[5];
    const float* beta2  = (const float*)d_in[6];
    const float* W2     = (const float*)d_in[7];
    const float* b2     = (const float*)d_in[8];
    const int*   coords = (const int*)d_in[9];
    float* out = (float*)d_out;   // 65536 x 128 fp32 (written only by conv2)

    char* ws = (char*)d_ws;
    unsigned short* h0b  = (unsigned short*)(ws);                    // 2 MB
    unsigned short* h1b  = (unsigned short*)(ws + (2u << 20));       // 16 MB, (o,p) layout
    unsigned short* Wc1f = (unsigned short*)(ws + (18u << 20));      // 2 MB
    unsigned short* Wp2  = (unsigned short*)(ws + (20u << 20));      // 864 KB
    int*   grid32        = (int*)  (ws + (21u << 20));               // 128 KB
    float* stats         = (float*)(ws + (21u << 20) + 131072);      // 512 B
    float* zpage         = (float*)(ws + (21u << 20) + 131072 + 512);// 512 B
    int*   idx_tab       = (int*)  (ws + (22u << 20));               // 7.08 MB
    int*   pidx27        = (int*)  (ws + (30u << 20));               // 864 KB

    // zero stats (128 f) + zpage (128 f) in one async memset
    hipMemsetAsync(stats, 0, 1024, stream);

    k1_kernel<<<288, 256, 0, stream>>>(coords, grid32, feats, stats + 0, stats + 32);
    k2_kernel<<<2104, 256, 0, stream>>>(coords, grid32, idx_tab, pidx27,
                                        W1, W2, Wc1f, Wp2,
                                        feats, stats + 0, stats + 32, gamma1, beta1, h0b);

    // conv1 folded -> bf16 h1b in (o,p) layout + fused GN2 stats
    conv1_fold_kernel<<<8 * (NPAR / 128), 256, 0, stream>>>(h0b, Wc1f, b1, pidx27,
                                                            h1b, zpage,
                                                            stats + 64, stats + 96);

    gn_apply_bf16_kernel<<<1024, 256, 0, stream>>>(h1b, stats + 64, stats + 96, gamma2, beta2, NCH);

    // conv2 (27 taps over children) -> fp32 out + residual repeat(feats,8)
    conv2_kernel<<<NCH / 128, 256, 0, stream>>>(h1b, Wp2, b2, idx_tab,
                                                feats, out, zpage);
}